// Round 8
// baseline (119.107 us; speedup 1.0000x reference)
//
#include <hip/hip_runtime.h>

#define N_NODESC 50000
#define NEMBEDC 128
#define HDIMC 256
#define NCLASSC 40
#define NBUCK 196        // ceil(50000/256)
#define BCAP 8192        // bucket capacity (mean ~4082)

typedef short short8v __attribute__((ext_vector_type(8)));
typedef float float4v __attribute__((ext_vector_type(4)));

// ---------------- ws layout (bytes) ----------------
// bcursor int[256]      @ 256     (zeroed by 1KB memset)
// deg     int[50176]    @ 4096
// offs    int[50176]    @ 204800
// wmh     bf16[12288]   @ 405504
// wml     bf16[12288]   @ 430080
// bmh     bf16[65536]   @ 458752
// bml     bf16[65536]   @ 589824
// csr16   u16[800000]   @ 720896   (ends 2320896)
// bbuf    u32[196*8192] @ 2359296  (ends 8781824)  -- dead after k_bsort
// xb      bf16[6400000] @ 15159296 (ends 27959296)

__device__ __forceinline__ void bsplit(float f, short* hi, short* lo) {
  unsigned u = __builtin_bit_cast(unsigned, f);
  unsigned hb = (u + 0x7FFFu + ((u >> 16) & 1u)) >> 16;
  *hi = (short)hb;
  float hf = __builtin_bit_cast(float, hb << 16);
  float r = f - hf;
  unsigned u2 = __builtin_bit_cast(unsigned, r);
  *lo = (short)((u2 + 0x7FFFu + ((u2 >> 16) & 1u)) >> 16);
}

__device__ __forceinline__ unsigned rbf(float f) {  // f32 -> bf16 bits (RN)
  unsigned u = __builtin_bit_cast(unsigned, f);
  return (u + 0x7FFFu + ((u >> 16) & 1u)) >> 16;
}

__device__ __forceinline__ float blo(unsigned v) {
  return __builtin_bit_cast(float, v << 16);
}
__device__ __forceinline__ float bhi(unsigned v) {
  return __builtin_bit_cast(float, v & 0xFFFF0000u);
}

// prep+bucket merged: blocks [0,3125) convert x->bf16; [3125,3429) build weight
// fragments; [3429, 3429+bg) bucket-scatter edges. bcursor pre-zeroed by memset.
__global__ __launch_bounds__(256) void k_prep_bucket(
    const float* __restrict__ x, const float* __restrict__ W_l,
    const float* __restrict__ W_r, const float* __restrict__ W_mlp,
    const int* __restrict__ e32, int E,
    unsigned short* __restrict__ xb,
    short* __restrict__ bh, short* __restrict__ bl,
    short* __restrict__ wh, short* __restrict__ wl,
    int* __restrict__ bcursor, unsigned* __restrict__ bbuf) {
  int blk = blockIdx.x;
  int tid = threadIdx.x;
  if (blk < 3125) {
    int i = (blk * 256 + tid) * 8;
    float4 a = *(const float4*)(x + i);
    float4 b = *(const float4*)(x + i + 4);
    float f[8] = {a.x, a.y, a.z, a.w, b.x, b.y, b.z, b.w};
    unsigned h[8];
#pragma unroll
    for (int j = 0; j < 8; ++j) h[j] = rbf(f[j]);
    uint4 o;
    o.x = h[0] | (h[1] << 16);
    o.y = h[2] | (h[3] << 16);
    o.z = h[4] | (h[5] << 16);
    o.w = h[6] | (h[7] << 16);
    *(uint4*)(xb + i) = o;
    return;
  }
  if (blk < 3429) {
    int i = (blk - 3125) * 256 + tid;
    if (i < 65536) {
      int e = i & 7, l = (i >> 3) & 63, nf = (i >> 9) & 15, ks = i >> 13;
      int k = ks * 32 + (l >> 4) * 8 + e;
      int n = nf * 16 + (l & 15);
      float v = (k < 128) ? W_l[n * 128 + k] : W_r[n * 128 + (k - 128)];
      short h, lo;
      bsplit(v, &h, &lo);
      bh[i] = h;
      bl[i] = lo;
    } else {
      int j = i - 65536;  // < 12288: [ks(8)][nf(3)][lane][8]
      int e = j & 7, l = (j >> 3) & 63, g = j >> 9;  // g < 24
      int nf = g % 3, ks = g / 3;
      int k = ks * 32 + (l >> 4) * 8 + e;
      int n = nf * 16 + (l & 15);
      float v = (n < NCLASSC) ? W_mlp[n * HDIMC + k] : 0.f;
      short h, lo;
      bsplit(v, &h, &lo);
      wh[j] = h;
      wl[j] = lo;
    }
    return;
  }
  // ---- bucket phase, with inline int64/int32 detection ----
  __shared__ int hist[NBUCK];
  __shared__ int sbase[NBUCK];
  __shared__ int s_is32;
  if (tid == 0) s_is32 = 0;
  if (tid < NBUCK) hist[tid] = 0;
  __syncthreads();
  int base = (blk - 3429) * 2048;
  {
    int e = base + tid;  // sample 256 odd-words of our own chunk
    if (e < E && e32[2 * e + 1] != 0) atomicOr(&s_is32, 1);
  }
  __syncthreads();
  int is64 = !s_is32;
  unsigned pe[8];
  int rk[8];
#pragma unroll
  for (int j = 0; j < 8; ++j) {
    int e = base + j * 256 + tid;
    pe[j] = 0xFFFFFFFFu;
    rk[j] = 0;
    if (e < E) {
      int src = is64 ? e32[2 * e] : e32[e];
      int dst = is64 ? e32[2 * E + 2 * e] : e32[E + e];
      pe[j] = ((unsigned)dst << 16) | (unsigned)src;
      rk[j] = atomicAdd(&hist[dst >> 8], 1);
    }
  }
  __syncthreads();
  if (tid < NBUCK) sbase[tid] = atomicAdd(&bcursor[tid], hist[tid]);
  __syncthreads();
#pragma unroll
  for (int j = 0; j < 8; ++j) {
    if (pe[j] != 0xFFFFFFFFu) {
      int b = pe[j] >> 24;
      int p = sbase[b] + rk[j];
      if (p < BCAP) bbuf[b * BCAP + p] = pe[j];
    }
  }
}

// Per-bucket 256-bin counting sort with inline global scan: emits deg, offs, csr16.
__global__ __launch_bounds__(256) void k_bsort(
    const unsigned* __restrict__ bbuf, const int* __restrict__ bcursor,
    int* __restrict__ deg, int* __restrict__ offs,
    unsigned short* __restrict__ csr16) {
  __shared__ int hist[256];
  __shared__ int off[256];
  __shared__ int cur[256];
  __shared__ int sscan[256];
  int tid = threadIdx.x;
  int b = blockIdx.x;
  int c = (tid < NBUCK) ? bcursor[tid] : 0;
  int v = c < BCAP ? c : BCAP;
  sscan[tid] = v;
  hist[tid] = 0;
  __syncthreads();
  for (int d = 1; d < 256; d <<= 1) {
    int t = (tid >= d) ? sscan[tid - d] : 0;
    __syncthreads();
    sscan[tid] += t;
    __syncthreads();
  }
  int cnt = bcursor[b];
  if (cnt > BCAP) cnt = BCAP;
  int ibase = b * BCAP;
  int cbase = sscan[b] - ((bcursor[b] < BCAP) ? bcursor[b] : BCAP);  // exclusive
  for (int i = tid; i < cnt; i += 256) {
    unsigned pe = bbuf[ibase + i];
    atomicAdd(&hist[(pe >> 16) & 255], 1);
  }
  __syncthreads();
  off[tid] = hist[tid];
  __syncthreads();
  for (int d = 1; d < 256; d <<= 1) {
    int t = (tid >= d) ? off[tid - d] : 0;
    __syncthreads();
    off[tid] += t;
    __syncthreads();
  }
  int ex = off[tid] - hist[tid];
  int n = (b << 8) + tid;
  deg[n] = hist[tid];
  offs[n] = cbase + ex;
  cur[tid] = ex;
  __syncthreads();
  for (int i = tid; i < cnt; i += 256) {
    unsigned pe = bbuf[ibase + i];
    int ln = (pe >> 16) & 255;
    int p = atomicAdd(&cur[ln], 1);
    csr16[cbase + p] = (unsigned short)(pe & 0xFFFFu);
  }
}

// Fully fused: per-block {aggregate 64 node-means into LDS, GEMM1, relu, GEMM2}.
// 8 waves; wave w aggregates nodes m0+w*8..+7 (quarter-wave uint4 gather +
// xor16/32 butterfly), writing bf16 means straight into the swizzled A-tile.
// A and h plain bf16; B and W_mlp split hi/lo (2-pass MFMA).
// launch_bounds (512,4): proven no-spill point; (512,6) spilled 57 MB (R5).
__global__ __launch_bounds__(512, 4) void k_fused_all(
    const unsigned short* __restrict__ xb, const unsigned short* __restrict__ csr16,
    const int* __restrict__ offs, const int* __restrict__ deg,
    const short* __restrict__ bmh, const short* __restrict__ bml,
    const short* __restrict__ wmh, const short* __restrict__ wml,
    const float* __restrict__ b_l, const float* __restrict__ b_mlp,
    float* __restrict__ out) {
  __shared__ short sh[16384];  // 32 KB: 64 rows x 256 bf16, XOR-swizzled; reused for h
  int t = threadIdx.x;
  int m0 = blockIdx.x * 64;
  int w = t >> 6, l = t & 63;

  // ---- stage xb half (kc 16..31) ----
#pragma unroll
  for (int r = 0; r < 2; ++r) {
    int c = t + 512 * r;        // 0..1023: 64 rows x 16 chunks-of-8-bf16
    int row = c >> 4, kc = 16 + (c & 15);
    int node = m0 + row;
    short8v v = (short8v){0, 0, 0, 0, 0, 0, 0, 0};
    if (node < N_NODESC) v = *(const short8v*)(xb + (size_t)node * 128 + (kc - 16) * 8);
    *(short8v*)&sh[row * 256 + ((kc ^ (row & 7)) << 3)] = v;
  }

  // ---- aggregate mean half (kc 0..15): 8 nodes per wave ----
  {
    int q = l >> 4;    // quarter id: which edge of the group of 4
    int ql = l & 15;   // 16 lanes x 16B = one 256B row
    const uint4* x4 = (const uint4*)xb;  // row s = x4[s*16 + ql]
    for (int i = 0; i < 8; ++i) {
      int node = m0 + w * 8 + i;
      if (node >= N_NODESC) break;
      int row = w * 8 + i;
      int beg = __builtin_amdgcn_readfirstlane(offs[node]);
      int d = __builtin_amdgcn_readfirstlane(deg[node]);
      float acc[8];
#pragma unroll
      for (int j = 0; j < 8; ++j) acc[j] = 0.f;
      int e = 0;
      for (; e + 8 <= d; e += 8) {
        int s0 = csr16[beg + e + q];
        int s1 = csr16[beg + e + 4 + q];
        uint4 v0 = x4[s0 * 16 + ql];
        uint4 v1 = x4[s1 * 16 + ql];
        unsigned w0[4] = {v0.x, v0.y, v0.z, v0.w};
        unsigned w1[4] = {v1.x, v1.y, v1.z, v1.w};
#pragma unroll
        for (int j = 0; j < 4; ++j) {
          acc[2 * j]     += blo(w0[j]) + blo(w1[j]);
          acc[2 * j + 1] += bhi(w0[j]) + bhi(w1[j]);
        }
      }
      if (e + 4 <= d) {
        int s0 = csr16[beg + e + q];
        uint4 v0 = x4[s0 * 16 + ql];
        unsigned w0[4] = {v0.x, v0.y, v0.z, v0.w};
#pragma unroll
        for (int j = 0; j < 4; ++j) {
          acc[2 * j]     += blo(w0[j]);
          acc[2 * j + 1] += bhi(w0[j]);
        }
        e += 4;
      }
      if (e < d) {               // tail 1..3 edges: only quarters q < r join
        int r = d - e;
        if (q < r) {
          int s0 = csr16[beg + e + q];
          uint4 v0 = x4[s0 * 16 + ql];
          unsigned w0[4] = {v0.x, v0.y, v0.z, v0.w};
#pragma unroll
          for (int j = 0; j < 4; ++j) {
            acc[2 * j]     += blo(w0[j]);
            acc[2 * j + 1] += bhi(w0[j]);
          }
        }
      }
#pragma unroll
      for (int j = 0; j < 8; ++j) {
        acc[j] += __shfl_xor(acc[j], 16);
        acc[j] += __shfl_xor(acc[j], 32);
      }
      if (l < 16) {
        float inv = 1.0f / (float)(d > 0 ? d : 1);
        uint4 o;
        o.x = rbf(acc[0] * inv) | (rbf(acc[1] * inv) << 16);
        o.y = rbf(acc[2] * inv) | (rbf(acc[3] * inv) << 16);
        o.z = rbf(acc[4] * inv) | (rbf(acc[5] * inv) << 16);
        o.w = rbf(acc[6] * inv) | (rbf(acc[7] * inv) << 16);
        *(uint4*)&sh[row * 256 + ((ql ^ (row & 7)) << 3)] = o;  // kc = ql
      }
    }
  }
  __syncthreads();

  int wm = w >> 2, wn = w & 3;   // wave tile: rows wm*32..+32, cols wn*64..+64
  int lr = l & 15, lg = l >> 4;

  float4v acc[2][4];
#pragma unroll
  for (int mi = 0; mi < 2; ++mi)
#pragma unroll
    for (int nj = 0; nj < 4; ++nj) acc[mi][nj] = (float4v){0.f, 0.f, 0.f, 0.f};

  // ---- GEMM1: h = A @ B, K=256 in 8 steps of 32, 2 passes (b_hi, b_lo) ----
  for (int ks = 0; ks < 8; ++ks) {
    short8v a[2];
#pragma unroll
    for (int mi = 0; mi < 2; ++mi) {
      int row = wm * 32 + mi * 16 + lr;
      int kc = ks * 4 + lg;
      a[mi] = *(short8v*)&sh[row * 256 + ((kc ^ (row & 7)) << 3)];
    }
    short8v bh4[4], bl4[4];
#pragma unroll
    for (int nj = 0; nj < 4; ++nj) {
      int fi = ((ks * 16 + wn * 4 + nj) * 64 + l) * 8;
      bh4[nj] = *(const short8v*)&bmh[fi];
      bl4[nj] = *(const short8v*)&bml[fi];
    }
#pragma unroll
    for (int mi = 0; mi < 2; ++mi)
#pragma unroll
      for (int nj = 0; nj < 4; ++nj) {
        acc[mi][nj] = __builtin_amdgcn_mfma_f32_16x16x32_bf16(a[mi], bh4[nj], acc[mi][nj], 0, 0, 0);
        acc[mi][nj] = __builtin_amdgcn_mfma_f32_16x16x32_bf16(a[mi], bl4[nj], acc[mi][nj], 0, 0, 0);
      }
  }
  __syncthreads();  // all waves done reading A

  // ---- epilogue 1: h = relu(acc + b_l) -> bf16 back into sh ----
#pragma unroll
  for (int mi = 0; mi < 2; ++mi)
#pragma unroll
    for (int nj = 0; nj < 4; ++nj) {
      int col = wn * 64 + nj * 16 + lr;
      float bb = b_l[col];
      int kc2 = col >> 3;
#pragma unroll
      for (int r = 0; r < 4; ++r) {
        int row = wm * 32 + mi * 16 + lg * 4 + r;
        float v = fmaxf(acc[mi][nj][r] + bb, 0.f);
        sh[row * 256 + ((kc2 ^ (row & 7)) << 3) + (col & 7)] = (short)rbf(v);
      }
    }
  __syncthreads();

  // ---- GEMM2: out = h @ Wmlp^T (48 padded cols), K=256, 2 passes ----
  int mf = w & 3;            // waves 0-3: nf {0,1}; waves 4-7: nf {2}
  float4v a2[2];
  a2[0] = (float4v){0.f, 0.f, 0.f, 0.f};
  a2[1] = a2[0];
  for (int ks = 0; ks < 8; ++ks) {
    int row = mf * 16 + lr;
    int kc = ks * 4 + lg;
    short8v hh = *(short8v*)&sh[row * 256 + ((kc ^ (row & 7)) << 3)];
#pragma unroll
    for (int u = 0; u < 2; ++u) {
      if (w >= 4 && u > 0) break;
      int nf = (w < 4) ? u : 2;
      int fi = ((ks * 3 + nf) * 64 + l) * 8;
      short8v wh8 = *(const short8v*)&wmh[fi];
      short8v wl8 = *(const short8v*)&wml[fi];
      a2[u] = __builtin_amdgcn_mfma_f32_16x16x32_bf16(hh, wh8, a2[u], 0, 0, 0);
      a2[u] = __builtin_amdgcn_mfma_f32_16x16x32_bf16(hh, wl8, a2[u], 0, 0, 0);
    }
  }
#pragma unroll
  for (int u = 0; u < 2; ++u) {
    if (w >= 4 && u > 0) break;
    int nf = (w < 4) ? u : 2;
    int col = nf * 16 + lr;
    if (col < NCLASSC) {
      float bb = b_mlp[col];
#pragma unroll
      for (int r = 0; r < 4; ++r) {
        int node = m0 + mf * 16 + lg * 4 + r;
        if (node < N_NODESC) out[node * NCLASSC + col] = a2[u][r] + bb;
      }
    }
  }
}

extern "C" void kernel_launch(void* const* d_in, const int* in_sizes, int n_in,
                              void* d_out, int out_size, void* d_ws, size_t ws_size,
                              hipStream_t stream) {
  const float* x     = (const float*)d_in[0];
  const float* W_l   = (const float*)d_in[1];
  const float* b_l   = (const float*)d_in[2];
  const float* W_r   = (const float*)d_in[3];
  const float* W_mlp = (const float*)d_in[4];
  const float* b_mlp = (const float*)d_in[5];
  const int*   e32   = (const int*)d_in[6];
  int E = in_sizes[6] / 2;
  float* out = (float*)d_out;

  char* ws = (char*)d_ws;
  int* bcursor     = (int*)(ws + 256);
  int* deg         = (int*)(ws + 4096);
  int* offs        = (int*)(ws + 204800);
  short* wmh       = (short*)(ws + 405504);
  short* wml       = (short*)(ws + 430080);
  short* bmh       = (short*)(ws + 458752);
  short* bml       = (short*)(ws + 589824);
  unsigned short* csr16 = (unsigned short*)(ws + 720896);
  unsigned* bbuf   = (unsigned*)(ws + 2359296);
  unsigned short* xb = (unsigned short*)(ws + 15159296);

  hipMemsetAsync(bcursor, 0, 1024, stream);
  int bg = (E + 2047) / 2048;
  k_prep_bucket<<<3429 + bg, 256, 0, stream>>>(x, W_l, W_r, W_mlp, e32, E, xb,
                                               bmh, bml, wmh, wml, bcursor, bbuf);
  k_bsort<<<NBUCK, 256, 0, stream>>>(bbuf, bcursor, deg, offs, csr16);
  k_fused_all<<<782, 512, 0, stream>>>(xb, csr16, offs, deg, bmh, bml, wmh, wml,
                                       b_l, b_mlp, out);
}

// Round 9
// 97.248 us; speedup vs baseline: 1.2248x; 1.2248x over previous
//
#include <hip/hip_runtime.h>

#define N_NODESC 50000
#define NEMBEDC 128
#define HDIMC 256
#define NCLASSC 40
#define NBUCK 196        // ceil(50000/256)
#define BCAP 8192        // bucket capacity (mean ~4082)

typedef short short8v __attribute__((ext_vector_type(8)));
typedef float float4v __attribute__((ext_vector_type(4)));

// ---------------- ws layout (bytes) ----------------
// bcursor int[256]      @ 256     (zeroed by 1KB memset)
// deg     int[50176]    @ 4096
// offs    int[50176]    @ 204800
// wmh     bf16[12288]   @ 405504
// bmh     bf16[65536]   @ 458752
// csr16   u16[800000]   @ 720896   (ends 2320896)
// bbuf    u32[196*8192] @ 2359296  (ends 8781824)  -- dead after k_bsort
// meanb   bf16[50000*128]@ 2359296 (ends 15159296) -- aliases bbuf (written later)
// xb      bf16[6400000] @ 15159296 (ends 27959296)

__device__ __forceinline__ unsigned rbf(float f) {  // f32 -> bf16 bits (RN)
  unsigned u = __builtin_bit_cast(unsigned, f);
  return (u + 0x7FFFu + ((u >> 16) & 1u)) >> 16;
}

__device__ __forceinline__ float blo(unsigned v) {
  return __builtin_bit_cast(float, v << 16);
}
__device__ __forceinline__ float bhi(unsigned v) {
  return __builtin_bit_cast(float, v & 0xFFFF0000u);
}

// prep+bucket merged: blocks [0,3125) convert x->bf16; [3125,3429) build bf16
// weight fragments (single precision, no lo-split); [3429,3429+bg) bucket-scatter.
__global__ __launch_bounds__(256) void k_prep_bucket(
    const float* __restrict__ x, const float* __restrict__ W_l,
    const float* __restrict__ W_r, const float* __restrict__ W_mlp,
    const int* __restrict__ e32, int E,
    unsigned short* __restrict__ xb,
    short* __restrict__ bh, short* __restrict__ wh,
    int* __restrict__ bcursor, unsigned* __restrict__ bbuf) {
  int blk = blockIdx.x;
  int tid = threadIdx.x;
  if (blk < 3125) {
    int i = (blk * 256 + tid) * 8;
    float4 a = *(const float4*)(x + i);
    float4 b = *(const float4*)(x + i + 4);
    float f[8] = {a.x, a.y, a.z, a.w, b.x, b.y, b.z, b.w};
    unsigned h[8];
#pragma unroll
    for (int j = 0; j < 8; ++j) h[j] = rbf(f[j]);
    uint4 o;
    o.x = h[0] | (h[1] << 16);
    o.y = h[2] | (h[3] << 16);
    o.z = h[4] | (h[5] << 16);
    o.w = h[6] | (h[7] << 16);
    *(uint4*)(xb + i) = o;
    return;
  }
  if (blk < 3429) {
    int i = (blk - 3125) * 256 + tid;
    if (i < 65536) {
      // B = [W_l | W_r], frag order: (ks, nf, lane, e) ->
      // B[k = ks*32 + (lane>>4)*8 + e][n = nf*16 + (lane&15)]
      int e = i & 7, l = (i >> 3) & 63, nf = (i >> 9) & 15, ks = i >> 13;
      int k = ks * 32 + (l >> 4) * 8 + e;
      int n = nf * 16 + (l & 15);
      float v = (k < 128) ? W_l[n * 128 + k] : W_r[n * 128 + (k - 128)];
      bh[i] = (short)rbf(v);
    } else {
      int j = i - 65536;  // < 12288: [ks(8)][nf(3)][lane][8], W_mlp padded to 48
      int e = j & 7, l = (j >> 3) & 63, g = j >> 9;  // g < 24
      int nf = g % 3, ks = g / 3;
      int k = ks * 32 + (l >> 4) * 8 + e;
      int n = nf * 16 + (l & 15);
      float v = (n < NCLASSC) ? W_mlp[n * HDIMC + k] : 0.f;
      wh[j] = (short)rbf(v);
    }
    return;
  }
  // ---- bucket phase, with inline int64/int32 detection ----
  __shared__ int hist[NBUCK];
  __shared__ int sbase[NBUCK];
  __shared__ int s_is32;
  if (tid == 0) s_is32 = 0;
  if (tid < NBUCK) hist[tid] = 0;
  __syncthreads();
  int base = (blk - 3429) * 2048;
  {
    int e = base + tid;  // sample 256 odd-words of our own chunk
    if (e < E && e32[2 * e + 1] != 0) atomicOr(&s_is32, 1);
  }
  __syncthreads();
  int is64 = !s_is32;
  unsigned pe[8];
  int rk[8];
#pragma unroll
  for (int j = 0; j < 8; ++j) {
    int e = base + j * 256 + tid;
    pe[j] = 0xFFFFFFFFu;
    rk[j] = 0;
    if (e < E) {
      int src = is64 ? e32[2 * e] : e32[e];
      int dst = is64 ? e32[2 * E + 2 * e] : e32[E + e];
      pe[j] = ((unsigned)dst << 16) | (unsigned)src;
      rk[j] = atomicAdd(&hist[dst >> 8], 1);
    }
  }
  __syncthreads();
  if (tid < NBUCK) sbase[tid] = atomicAdd(&bcursor[tid], hist[tid]);
  __syncthreads();
#pragma unroll
  for (int j = 0; j < 8; ++j) {
    if (pe[j] != 0xFFFFFFFFu) {
      int b = pe[j] >> 24;
      int p = sbase[b] + rk[j];
      if (p < BCAP) bbuf[b * BCAP + p] = pe[j];
    }
  }
}

// Per-bucket 256-bin counting sort with inline global scan: emits deg, offs, csr16.
__global__ __launch_bounds__(256) void k_bsort(
    const unsigned* __restrict__ bbuf, const int* __restrict__ bcursor,
    int* __restrict__ deg, int* __restrict__ offs,
    unsigned short* __restrict__ csr16) {
  __shared__ int hist[256];
  __shared__ int off[256];
  __shared__ int cur[256];
  __shared__ int sscan[256];
  int tid = threadIdx.x;
  int b = blockIdx.x;
  int c = (tid < NBUCK) ? bcursor[tid] : 0;
  int v = c < BCAP ? c : BCAP;
  sscan[tid] = v;
  hist[tid] = 0;
  __syncthreads();
  for (int d = 1; d < 256; d <<= 1) {
    int t = (tid >= d) ? sscan[tid - d] : 0;
    __syncthreads();
    sscan[tid] += t;
    __syncthreads();
  }
  int cnt = bcursor[b];
  if (cnt > BCAP) cnt = BCAP;
  int ibase = b * BCAP;
  int cbase = sscan[b] - ((bcursor[b] < BCAP) ? bcursor[b] : BCAP);  // exclusive
  for (int i = tid; i < cnt; i += 256) {
    unsigned pe = bbuf[ibase + i];
    atomicAdd(&hist[(pe >> 16) & 255], 1);
  }
  __syncthreads();
  off[tid] = hist[tid];
  __syncthreads();
  for (int d = 1; d < 256; d <<= 1) {
    int t = (tid >= d) ? off[tid - d] : 0;
    __syncthreads();
    off[tid] += t;
    __syncthreads();
  }
  int ex = off[tid] - hist[tid];
  int n = (b << 8) + tid;
  deg[n] = hist[tid];
  offs[n] = cbase + ex;
  cur[tid] = ex;
  __syncthreads();
  for (int i = tid; i < cnt; i += 256) {
    unsigned pe = bbuf[ibase + i];
    int ln = (pe >> 16) & 255;
    int p = atomicAdd(&cur[ln], 1);
    csr16[cbase + p] = (unsigned short)(pe & 0xFFFFu);
  }
}

// One wave per node. uint4 gather: 16B/lane, quarter-wave per row => 4 rows/load.
// Quarter q accumulates edges e+q; final butterfly (xor 16, 32) sums quarters.
__global__ __launch_bounds__(512) void k_aggregate_bf(
    const unsigned short* __restrict__ xb, const unsigned short* __restrict__ csr16,
    const int* __restrict__ offs, const int* __restrict__ deg,
    unsigned* __restrict__ meanb32) {
  int wave = threadIdx.x >> 6;
  int lane = threadIdx.x & 63;
  int node = blockIdx.x * 8 + wave;
  if (node >= N_NODESC) return;
  int beg = __builtin_amdgcn_readfirstlane(offs[node]);
  int d = __builtin_amdgcn_readfirstlane(deg[node]);
  int q = lane >> 4;    // quarter id: which edge of the group of 4
  int ql = lane & 15;   // 16 lanes x 16B = one 256B row
  const uint4* x4 = (const uint4*)xb;  // row s = x4[s*16 + ql]
  float acc[8];
#pragma unroll
  for (int i = 0; i < 8; ++i) acc[i] = 0.f;
  int e = 0;
  for (; e + 8 <= d; e += 8) {
    int s0 = csr16[beg + e + q];
    int s1 = csr16[beg + e + 4 + q];
    uint4 v0 = x4[s0 * 16 + ql];
    uint4 v1 = x4[s1 * 16 + ql];
    unsigned w0[4] = {v0.x, v0.y, v0.z, v0.w};
    unsigned w1[4] = {v1.x, v1.y, v1.z, v1.w};
#pragma unroll
    for (int i = 0; i < 4; ++i) {
      acc[2 * i]     += blo(w0[i]) + blo(w1[i]);
      acc[2 * i + 1] += bhi(w0[i]) + bhi(w1[i]);
    }
  }
  if (e + 4 <= d) {
    int s0 = csr16[beg + e + q];
    uint4 v0 = x4[s0 * 16 + ql];
    unsigned w0[4] = {v0.x, v0.y, v0.z, v0.w};
#pragma unroll
    for (int i = 0; i < 4; ++i) {
      acc[2 * i]     += blo(w0[i]);
      acc[2 * i + 1] += bhi(w0[i]);
    }
    e += 4;
  }
  if (e < d) {                 // tail 1..3 edges: only quarters q < r join
    int r = d - e;
    if (q < r) {
      int s0 = csr16[beg + e + q];
      uint4 v0 = x4[s0 * 16 + ql];
      unsigned w0[4] = {v0.x, v0.y, v0.z, v0.w};
#pragma unroll
      for (int i = 0; i < 4; ++i) {
        acc[2 * i]     += blo(w0[i]);
        acc[2 * i + 1] += bhi(w0[i]);
      }
    }
  }
  // combine quarters: lanes l, l^16, l^32, l^48 hold same dims
#pragma unroll
  for (int i = 0; i < 8; ++i) {
    acc[i] += __shfl_xor(acc[i], 16);
    acc[i] += __shfl_xor(acc[i], 32);
  }
  if (lane < 16) {
    float inv = 1.0f / (float)(d > 0 ? d : 1);
    uint4 o;
    o.x = rbf(acc[0] * inv) | (rbf(acc[1] * inv) << 16);
    o.y = rbf(acc[2] * inv) | (rbf(acc[3] * inv) << 16);
    o.z = rbf(acc[4] * inv) | (rbf(acc[5] * inv) << 16);
    o.w = rbf(acc[6] * inv) | (rbf(acc[7] * inv) << 16);
    ((uint4*)(meanb32 + (size_t)node * 64))[lane] = o;
  }
}

// Fused GEMM1+GEMM2 via MFMA, all operands plain bf16 (single pass).
// Block: 64 nodes x full 256 hdim. 8 waves, wave tile 32x64. 32 KB LDS.
// launch_bounds (512,4): proven no-spill point; (512,6) spilled 57 MB (R5).
__global__ __launch_bounds__(512, 4) void k_fused_mfma(
    const unsigned short* __restrict__ meanb, const unsigned short* __restrict__ xb,
    const short* __restrict__ bmh, const short* __restrict__ wmh,
    const float* __restrict__ b_l, const float* __restrict__ b_mlp,
    float* __restrict__ out) {
  __shared__ short sh[16384];  // 32 KB: 64 rows x 256 bf16, XOR-swizzled; reused for h
  int t = threadIdx.x;
  int m0 = blockIdx.x * 64;

  // ---- stage A = [meanb | xb] rows m0..m0+63 (pure copies, no conversion) ----
#pragma unroll
  for (int r = 0; r < 4; ++r) {
    int c = t + 512 * r;        // 0..2047: 64 rows x 32 chunks-of-8-bf16
    int row = c >> 5, kc = c & 31;
    int node = m0 + row;
    short8v v = (short8v){0, 0, 0, 0, 0, 0, 0, 0};
    if (node < N_NODESC) {
      const unsigned short* src = (kc < 16) ? (meanb + (size_t)node * 128 + kc * 8)
                                            : (xb + (size_t)node * 128 + (kc - 16) * 8);
      v = *(const short8v*)src;
    }
    *(short8v*)&sh[row * 256 + ((kc ^ (row & 7)) << 3)] = v;
  }
  __syncthreads();

  int w = t >> 6, l = t & 63;
  int wm = w >> 2, wn = w & 3;   // wave tile: rows wm*32..+32, cols wn*64..+64
  int lr = l & 15, lg = l >> 4;

  float4v acc[2][4];
#pragma unroll
  for (int mi = 0; mi < 2; ++mi)
#pragma unroll
    for (int nj = 0; nj < 4; ++nj) acc[mi][nj] = (float4v){0.f, 0.f, 0.f, 0.f};

  // ---- GEMM1: h = A @ B, K=256 in 8 steps of 32, single bf16 pass ----
  for (int ks = 0; ks < 8; ++ks) {
    short8v a[2];
#pragma unroll
    for (int mi = 0; mi < 2; ++mi) {
      int row = wm * 32 + mi * 16 + lr;
      int kc = ks * 4 + lg;
      a[mi] = *(short8v*)&sh[row * 256 + ((kc ^ (row & 7)) << 3)];
    }
    short8v bh4[4];
#pragma unroll
    for (int nj = 0; nj < 4; ++nj) {
      int fi = ((ks * 16 + wn * 4 + nj) * 64 + l) * 8;
      bh4[nj] = *(const short8v*)&bmh[fi];
    }
#pragma unroll
    for (int mi = 0; mi < 2; ++mi)
#pragma unroll
      for (int nj = 0; nj < 4; ++nj)
        acc[mi][nj] = __builtin_amdgcn_mfma_f32_16x16x32_bf16(a[mi], bh4[nj], acc[mi][nj], 0, 0, 0);
  }
  __syncthreads();  // all waves done reading A

  // ---- epilogue 1: h = relu(acc + b_l) -> bf16 back into sh ----
#pragma unroll
  for (int mi = 0; mi < 2; ++mi)
#pragma unroll
    for (int nj = 0; nj < 4; ++nj) {
      int col = wn * 64 + nj * 16 + lr;
      float bb = b_l[col];
      int kc2 = col >> 3;
#pragma unroll
      for (int r = 0; r < 4; ++r) {
        int row = wm * 32 + mi * 16 + lg * 4 + r;
        float v = fmaxf(acc[mi][nj][r] + bb, 0.f);
        sh[row * 256 + ((kc2 ^ (row & 7)) << 3) + (col & 7)] = (short)rbf(v);
      }
    }
  __syncthreads();

  // ---- GEMM2: out = h @ Wmlp^T (48 padded cols), K=256, single pass ----
  int mf = w & 3;            // waves 0-3: nf {0,1}; waves 4-7: nf {2}
  float4v a2[2];
  a2[0] = (float4v){0.f, 0.f, 0.f, 0.f};
  a2[1] = a2[0];
  for (int ks = 0; ks < 8; ++ks) {
    int row = mf * 16 + lr;
    int kc = ks * 4 + lg;
    short8v hh = *(short8v*)&sh[row * 256 + ((kc ^ (row & 7)) << 3)];
#pragma unroll
    for (int u = 0; u < 2; ++u) {
      if (w >= 4 && u > 0) break;
      int nf = (w < 4) ? u : 2;
      int fi = ((ks * 3 + nf) * 64 + l) * 8;
      short8v wh8 = *(const short8v*)&wmh[fi];
      a2[u] = __builtin_amdgcn_mfma_f32_16x16x32_bf16(hh, wh8, a2[u], 0, 0, 0);
    }
  }
#pragma unroll
  for (int u = 0; u < 2; ++u) {
    if (w >= 4 && u > 0) break;
    int nf = (w < 4) ? u : 2;
    int col = nf * 16 + lr;
    if (col < NCLASSC) {
      float bb = b_mlp[col];
#pragma unroll
      for (int r = 0; r < 4; ++r) {
        int node = m0 + mf * 16 + lg * 4 + r;
        if (node < N_NODESC) out[node * NCLASSC + col] = a2[u][r] + bb;
      }
    }
  }
}

extern "C" void kernel_launch(void* const* d_in, const int* in_sizes, int n_in,
                              void* d_out, int out_size, void* d_ws, size_t ws_size,
                              hipStream_t stream) {
  const float* x     = (const float*)d_in[0];
  const float* W_l   = (const float*)d_in[1];
  const float* b_l   = (const float*)d_in[2];
  const float* W_r   = (const float*)d_in[3];
  const float* W_mlp = (const float*)d_in[4];
  const float* b_mlp = (const float*)d_in[5];
  const int*   e32   = (const int*)d_in[6];
  int E = in_sizes[6] / 2;
  float* out = (float*)d_out;

  char* ws = (char*)d_ws;
  int* bcursor     = (int*)(ws + 256);
  int* deg         = (int*)(ws + 4096);
  int* offs        = (int*)(ws + 204800);
  short* wmh       = (short*)(ws + 405504);
  short* bmh       = (short*)(ws + 458752);
  unsigned short* csr16 = (unsigned short*)(ws + 720896);
  unsigned* bbuf   = (unsigned*)(ws + 2359296);
  unsigned short* meanb = (unsigned short*)(ws + 2359296);  // aliases bbuf (dead first)
  unsigned short* xb = (unsigned short*)(ws + 15159296);

  hipMemsetAsync(bcursor, 0, 1024, stream);
  int bg = (E + 2047) / 2048;
  k_prep_bucket<<<3429 + bg, 256, 0, stream>>>(x, W_l, W_r, W_mlp, e32, E, xb,
                                               bmh, wmh, bcursor, bbuf);
  k_bsort<<<NBUCK, 256, 0, stream>>>(bbuf, bcursor, deg, offs, csr16);
  k_aggregate_bf<<<6250, 512, 0, stream>>>(xb, csr16, offs, deg, (unsigned*)meanb);
  k_fused_mfma<<<782, 512, 0, stream>>>(meanb, xb, bmh, wmh, b_l, b_mlp, out);
}

// Round 10
// 96.685 us; speedup vs baseline: 1.2319x; 1.0058x over previous
//
#include <hip/hip_runtime.h>

#define N_NODESC 50000
#define NEMBEDC 128
#define HDIMC 256
#define NCLASSC 40
#define NBUCK 196        // ceil(50000/256)
#define BCAP 8192        // bucket capacity (mean ~4082)

typedef short short8v __attribute__((ext_vector_type(8)));
typedef float float4v __attribute__((ext_vector_type(4)));

// ---------------- ws layout (bytes) ----------------
// bcursor int[256]      @ 256     (zeroed by 1KB memset)
// deg     int[50176]    @ 4096
// offs    int[50176]    @ 204800
// wmh     bf16[12288]   @ 405504
// bmh     bf16[65536]   @ 458752
// csr16   u16[800000]   @ 720896   (ends 2320896)
// bbuf    u32[196*8192] @ 2359296  (ends 8781824)  -- dead after k_bsort
// meanb   bf16[50000*128]@ 2359296 (ends 15159296) -- aliases bbuf (written later)
// xb      bf16[6400000] @ 15159296 (ends 27959296)

__device__ __forceinline__ unsigned rbf(float f) {  // f32 -> bf16 bits (RN)
  unsigned u = __builtin_bit_cast(unsigned, f);
  return (u + 0x7FFFu + ((u >> 16) & 1u)) >> 16;
}

__device__ __forceinline__ float blo(unsigned v) {
  return __builtin_bit_cast(float, v << 16);
}
__device__ __forceinline__ float bhi(unsigned v) {
  return __builtin_bit_cast(float, v & 0xFFFF0000u);
}

// prep+bucket merged: blocks [0,3125) convert x->bf16; [3125,3429) build bf16
// weight fragments; [3429,3429+bg) bucket-scatter. bcursor pre-zeroed by memset.
__global__ __launch_bounds__(256) void k_prep_bucket(
    const float* __restrict__ x, const float* __restrict__ W_l,
    const float* __restrict__ W_r, const float* __restrict__ W_mlp,
    const int* __restrict__ e32, int E,
    unsigned short* __restrict__ xb,
    short* __restrict__ bh, short* __restrict__ wh,
    int* __restrict__ bcursor, unsigned* __restrict__ bbuf) {
  int blk = blockIdx.x;
  int tid = threadIdx.x;
  if (blk < 3125) {
    int i = (blk * 256 + tid) * 8;
    float4 a = *(const float4*)(x + i);
    float4 b = *(const float4*)(x + i + 4);
    float f[8] = {a.x, a.y, a.z, a.w, b.x, b.y, b.z, b.w};
    unsigned h[8];
#pragma unroll
    for (int j = 0; j < 8; ++j) h[j] = rbf(f[j]);
    uint4 o;
    o.x = h[0] | (h[1] << 16);
    o.y = h[2] | (h[3] << 16);
    o.z = h[4] | (h[5] << 16);
    o.w = h[6] | (h[7] << 16);
    *(uint4*)(xb + i) = o;
    return;
  }
  if (blk < 3429) {
    int i = (blk - 3125) * 256 + tid;
    if (i < 65536) {
      // B = [W_l | W_r], frag order: (ks, nf, lane, e) ->
      // B[k = ks*32 + (lane>>4)*8 + e][n = nf*16 + (lane&15)]
      int e = i & 7, l = (i >> 3) & 63, nf = (i >> 9) & 15, ks = i >> 13;
      int k = ks * 32 + (l >> 4) * 8 + e;
      int n = nf * 16 + (l & 15);
      float v = (k < 128) ? W_l[n * 128 + k] : W_r[n * 128 + (k - 128)];
      bh[i] = (short)rbf(v);
    } else {
      int j = i - 65536;  // < 12288: [ks(8)][nf(3)][lane][8], W_mlp padded to 48
      int e = j & 7, l = (j >> 3) & 63, g = j >> 9;  // g < 24
      int nf = g % 3, ks = g / 3;
      int k = ks * 32 + (l >> 4) * 8 + e;
      int n = nf * 16 + (l & 15);
      float v = (n < NCLASSC) ? W_mlp[n * HDIMC + k] : 0.f;
      wh[j] = (short)rbf(v);
    }
    return;
  }
  // ---- bucket phase, with inline int64/int32 detection ----
  __shared__ int hist[NBUCK];
  __shared__ int sbase[NBUCK];
  __shared__ int s_is32;
  if (tid == 0) s_is32 = 0;
  if (tid < NBUCK) hist[tid] = 0;
  __syncthreads();
  int base = (blk - 3429) * 2048;
  {
    int e = base + tid;  // sample 256 odd-words of our own chunk
    if (e < E && e32[2 * e + 1] != 0) atomicOr(&s_is32, 1);
  }
  __syncthreads();
  int is64 = !s_is32;
  unsigned pe[8];
  int rk[8];
#pragma unroll
  for (int j = 0; j < 8; ++j) {
    int e = base + j * 256 + tid;
    pe[j] = 0xFFFFFFFFu;
    rk[j] = 0;
    if (e < E) {
      int src = is64 ? e32[2 * e] : e32[e];
      int dst = is64 ? e32[2 * E + 2 * e] : e32[E + e];
      pe[j] = ((unsigned)dst << 16) | (unsigned)src;
      rk[j] = atomicAdd(&hist[dst >> 8], 1);
    }
  }
  __syncthreads();
  if (tid < NBUCK) sbase[tid] = atomicAdd(&bcursor[tid], hist[tid]);
  __syncthreads();
#pragma unroll
  for (int j = 0; j < 8; ++j) {
    if (pe[j] != 0xFFFFFFFFu) {
      int b = pe[j] >> 24;
      int p = sbase[b] + rk[j];
      if (p < BCAP) bbuf[b * BCAP + p] = pe[j];
    }
  }
}

// Per-bucket 256-bin counting sort with inline global scan: emits deg, offs, csr16.
__global__ __launch_bounds__(256) void k_bsort(
    const unsigned* __restrict__ bbuf, const int* __restrict__ bcursor,
    int* __restrict__ deg, int* __restrict__ offs,
    unsigned short* __restrict__ csr16) {
  __shared__ int hist[256];
  __shared__ int off[256];
  __shared__ int cur[256];
  __shared__ int sscan[256];
  int tid = threadIdx.x;
  int b = blockIdx.x;
  int c = (tid < NBUCK) ? bcursor[tid] : 0;
  int v = c < BCAP ? c : BCAP;
  sscan[tid] = v;
  hist[tid] = 0;
  __syncthreads();
  for (int d = 1; d < 256; d <<= 1) {
    int t = (tid >= d) ? sscan[tid - d] : 0;
    __syncthreads();
    sscan[tid] += t;
    __syncthreads();
  }
  int cnt = bcursor[b];
  if (cnt > BCAP) cnt = BCAP;
  int ibase = b * BCAP;
  int cbase = sscan[b] - ((bcursor[b] < BCAP) ? bcursor[b] : BCAP);  // exclusive
  for (int i = tid; i < cnt; i += 256) {
    unsigned pe = bbuf[ibase + i];
    atomicAdd(&hist[(pe >> 16) & 255], 1);
  }
  __syncthreads();
  off[tid] = hist[tid];
  __syncthreads();
  for (int d = 1; d < 256; d <<= 1) {
    int t = (tid >= d) ? off[tid - d] : 0;
    __syncthreads();
    off[tid] += t;
    __syncthreads();
  }
  int ex = off[tid] - hist[tid];
  int n = (b << 8) + tid;
  deg[n] = hist[tid];
  offs[n] = cbase + ex;
  cur[tid] = ex;
  __syncthreads();
  for (int i = tid; i < cnt; i += 256) {
    unsigned pe = bbuf[ibase + i];
    int ln = (pe >> 16) & 255;
    int p = atomicAdd(&cur[ln], 1);
    csr16[cbase + p] = (unsigned short)(pe & 0xFFFFu);
  }
}

// One wave per node. uint4 gather: 16B/lane, quarter-wave per row => 4 rows/load.
// 16-deep unroll: 4 independent row-gathers in flight per wave (MLP).
// launch_bounds (512,8) pins VGPR <= 64 (m69 cliff: 32 waves/CU).
__global__ __launch_bounds__(512, 8) void k_aggregate_bf(
    const unsigned short* __restrict__ xb, const unsigned short* __restrict__ csr16,
    const int* __restrict__ offs, const int* __restrict__ deg,
    unsigned* __restrict__ meanb32) {
  int wave = threadIdx.x >> 6;
  int lane = threadIdx.x & 63;
  int node = blockIdx.x * 8 + wave;
  if (node >= N_NODESC) return;
  int beg = __builtin_amdgcn_readfirstlane(offs[node]);
  int d = __builtin_amdgcn_readfirstlane(deg[node]);
  int q = lane >> 4;    // quarter id: which edge of the group of 4
  int ql = lane & 15;   // 16 lanes x 16B = one 256B row
  const uint4* x4 = (const uint4*)xb;  // row s = x4[s*16 + ql]
  float acc[8];
#pragma unroll
  for (int i = 0; i < 8; ++i) acc[i] = 0.f;
  int e = 0;
  for (; e + 16 <= d; e += 16) {
    int s0 = csr16[beg + e + q];
    int s1 = csr16[beg + e + 4 + q];
    int s2 = csr16[beg + e + 8 + q];
    int s3 = csr16[beg + e + 12 + q];
    uint4 v0 = x4[s0 * 16 + ql];
    uint4 v1 = x4[s1 * 16 + ql];
    uint4 v2 = x4[s2 * 16 + ql];
    uint4 v3 = x4[s3 * 16 + ql];
    unsigned w0[4] = {v0.x, v0.y, v0.z, v0.w};
    unsigned w1[4] = {v1.x, v1.y, v1.z, v1.w};
    unsigned w2[4] = {v2.x, v2.y, v2.z, v2.w};
    unsigned w3[4] = {v3.x, v3.y, v3.z, v3.w};
#pragma unroll
    for (int i = 0; i < 4; ++i) {
      acc[2 * i]     += (blo(w0[i]) + blo(w1[i])) + (blo(w2[i]) + blo(w3[i]));
      acc[2 * i + 1] += (bhi(w0[i]) + bhi(w1[i])) + (bhi(w2[i]) + bhi(w3[i]));
    }
  }
  if (e + 8 <= d) {
    int s0 = csr16[beg + e + q];
    int s1 = csr16[beg + e + 4 + q];
    uint4 v0 = x4[s0 * 16 + ql];
    uint4 v1 = x4[s1 * 16 + ql];
    unsigned w0[4] = {v0.x, v0.y, v0.z, v0.w};
    unsigned w1[4] = {v1.x, v1.y, v1.z, v1.w};
#pragma unroll
    for (int i = 0; i < 4; ++i) {
      acc[2 * i]     += blo(w0[i]) + blo(w1[i]);
      acc[2 * i + 1] += bhi(w0[i]) + bhi(w1[i]);
    }
    e += 8;
  }
  if (e + 4 <= d) {
    int s0 = csr16[beg + e + q];
    uint4 v0 = x4[s0 * 16 + ql];
    unsigned w0[4] = {v0.x, v0.y, v0.z, v0.w};
#pragma unroll
    for (int i = 0; i < 4; ++i) {
      acc[2 * i]     += blo(w0[i]);
      acc[2 * i + 1] += bhi(w0[i]);
    }
    e += 4;
  }
  if (e < d) {                 // tail 1..3 edges: only quarters q < r join
    int r = d - e;
    if (q < r) {
      int s0 = csr16[beg + e + q];
      uint4 v0 = x4[s0 * 16 + ql];
      unsigned w0[4] = {v0.x, v0.y, v0.z, v0.w};
#pragma unroll
      for (int i = 0; i < 4; ++i) {
        acc[2 * i]     += blo(w0[i]);
        acc[2 * i + 1] += bhi(w0[i]);
      }
    }
  }
  // combine quarters: lanes l, l^16, l^32, l^48 hold same dims
#pragma unroll
  for (int i = 0; i < 8; ++i) {
    acc[i] += __shfl_xor(acc[i], 16);
    acc[i] += __shfl_xor(acc[i], 32);
  }
  if (lane < 16) {
    float inv = 1.0f / (float)(d > 0 ? d : 1);
    uint4 o;
    o.x = rbf(acc[0] * inv) | (rbf(acc[1] * inv) << 16);
    o.y = rbf(acc[2] * inv) | (rbf(acc[3] * inv) << 16);
    o.z = rbf(acc[4] * inv) | (rbf(acc[5] * inv) << 16);
    o.w = rbf(acc[6] * inv) | (rbf(acc[7] * inv) << 16);
    ((uint4*)(meanb32 + (size_t)node * 64))[lane] = o;
  }
}

// Fused GEMM1+GEMM2 via MFMA, all operands plain bf16 (single pass).
// Block: 64 nodes x full 256 hdim. 8 waves, wave tile 32x64. 32 KB LDS.
// VGPR=60 (just under the 64 cliff -> 4 blocks/CU); do NOT add unrolling here.
__global__ __launch_bounds__(512, 4) void k_fused_mfma(
    const unsigned short* __restrict__ meanb, const unsigned short* __restrict__ xb,
    const short* __restrict__ bmh, const short* __restrict__ wmh,
    const float* __restrict__ b_l, const float* __restrict__ b_mlp,
    float* __restrict__ out) {
  __shared__ short sh[16384];  // 32 KB: 64 rows x 256 bf16, XOR-swizzled; reused for h
  int t = threadIdx.x;
  int m0 = blockIdx.x * 64;

  // ---- stage A = [meanb | xb] rows m0..m0+63 (pure copies, no conversion) ----
#pragma unroll
  for (int r = 0; r < 4; ++r) {
    int c = t + 512 * r;        // 0..2047: 64 rows x 32 chunks-of-8-bf16
    int row = c >> 5, kc = c & 31;
    int node = m0 + row;
    short8v v = (short8v){0, 0, 0, 0, 0, 0, 0, 0};
    if (node < N_NODESC) {
      const unsigned short* src = (kc < 16) ? (meanb + (size_t)node * 128 + kc * 8)
                                            : (xb + (size_t)node * 128 + (kc - 16) * 8);
      v = *(const short8v*)src;
    }
    *(short8v*)&sh[row * 256 + ((kc ^ (row & 7)) << 3)] = v;
  }
  __syncthreads();

  int w = t >> 6, l = t & 63;
  int wm = w >> 2, wn = w & 3;   // wave tile: rows wm*32..+32, cols wn*64..+64
  int lr = l & 15, lg = l >> 4;

  float4v acc[2][4];
#pragma unroll
  for (int mi = 0; mi < 2; ++mi)
#pragma unroll
    for (int nj = 0; nj < 4; ++nj) acc[mi][nj] = (float4v){0.f, 0.f, 0.f, 0.f};

  // ---- GEMM1: h = A @ B, K=256 in 8 steps of 32, single bf16 pass ----
  for (int ks = 0; ks < 8; ++ks) {
    short8v a[2];
#pragma unroll
    for (int mi = 0; mi < 2; ++mi) {
      int row = wm * 32 + mi * 16 + lr;
      int kc = ks * 4 + lg;
      a[mi] = *(short8v*)&sh[row * 256 + ((kc ^ (row & 7)) << 3)];
    }
    short8v bh4[4];
#pragma unroll
    for (int nj = 0; nj < 4; ++nj) {
      int fi = ((ks * 16 + wn * 4 + nj) * 64 + l) * 8;
      bh4[nj] = *(const short8v*)&bmh[fi];
    }
#pragma unroll
    for (int mi = 0; mi < 2; ++mi)
#pragma unroll
      for (int nj = 0; nj < 4; ++nj)
        acc[mi][nj] = __builtin_amdgcn_mfma_f32_16x16x32_bf16(a[mi], bh4[nj], acc[mi][nj], 0, 0, 0);
  }
  __syncthreads();  // all waves done reading A

  // ---- epilogue 1: h = relu(acc + b_l) -> bf16 back into sh ----
#pragma unroll
  for (int mi = 0; mi < 2; ++mi)
#pragma unroll
    for (int nj = 0; nj < 4; ++nj) {
      int col = wn * 64 + nj * 16 + lr;
      float bb = b_l[col];
      int kc2 = col >> 3;
#pragma unroll
      for (int r = 0; r < 4; ++r) {
        int row = wm * 32 + mi * 16 + lg * 4 + r;
        float v = fmaxf(acc[mi][nj][r] + bb, 0.f);
        sh[row * 256 + ((kc2 ^ (row & 7)) << 3) + (col & 7)] = (short)rbf(v);
      }
    }
  __syncthreads();

  // ---- GEMM2: out = h @ Wmlp^T (48 padded cols), K=256, single pass ----
  int mf = w & 3;            // waves 0-3: nf {0,1}; waves 4-7: nf {2}
  float4v a2[2];
  a2[0] = (float4v){0.f, 0.f, 0.f, 0.f};
  a2[1] = a2[0];
  for (int ks = 0; ks < 8; ++ks) {
    int row = mf * 16 + lr;
    int kc = ks * 4 + lg;
    short8v hh = *(short8v*)&sh[row * 256 + ((kc ^ (row & 7)) << 3)];
#pragma unroll
    for (int u = 0; u < 2; ++u) {
      if (w >= 4 && u > 0) break;
      int nf = (w < 4) ? u : 2;
      int fi = ((ks * 3 + nf) * 64 + l) * 8;
      short8v wh8 = *(const short8v*)&wmh[fi];
      a2[u] = __builtin_amdgcn_mfma_f32_16x16x32_bf16(hh, wh8, a2[u], 0, 0, 0);
    }
  }
#pragma unroll
  for (int u = 0; u < 2; ++u) {
    if (w >= 4 && u > 0) break;
    int nf = (w < 4) ? u : 2;
    int col = nf * 16 + lr;
    if (col < NCLASSC) {
      float bb = b_mlp[col];
#pragma unroll
      for (int r = 0; r < 4; ++r) {
        int node = m0 + mf * 16 + lg * 4 + r;
        if (node < N_NODESC) out[node * NCLASSC + col] = a2[u][r] + bb;
      }
    }
  }
}

extern "C" void kernel_launch(void* const* d_in, const int* in_sizes, int n_in,
                              void* d_out, int out_size, void* d_ws, size_t ws_size,
                              hipStream_t stream) {
  const float* x     = (const float*)d_in[0];
  const float* W_l   = (const float*)d_in[1];
  const float* b_l   = (const float*)d_in[2];
  const float* W_r   = (const float*)d_in[3];
  const float* W_mlp = (const float*)d_in[4];
  const float* b_mlp = (const float*)d_in[5];
  const int*   e32   = (const int*)d_in[6];
  int E = in_sizes[6] / 2;
  float* out = (float*)d_out;

  char* ws = (char*)d_ws;
  int* bcursor     = (int*)(ws + 256);
  int* deg         = (int*)(ws + 4096);
  int* offs        = (int*)(ws + 204800);
  short* wmh       = (short*)(ws + 405504);
  short* bmh       = (short*)(ws + 458752);
  unsigned short* csr16 = (unsigned short*)(ws + 720896);
  unsigned* bbuf   = (unsigned*)(ws + 2359296);
  unsigned short* meanb = (unsigned short*)(ws + 2359296);  // aliases bbuf (dead first)
  unsigned short* xb = (unsigned short*)(ws + 15159296);

  hipMemsetAsync(bcursor, 0, 1024, stream);
  int bg = (E + 2047) / 2048;
  k_prep_bucket<<<3429 + bg, 256, 0, stream>>>(x, W_l, W_r, W_mlp, e32, E, xb,
                                               bmh, wmh, bcursor, bbuf);
  k_bsort<<<NBUCK, 256, 0, stream>>>(bbuf, bcursor, deg, offs, csr16);
  k_aggregate_bf<<<6250, 512, 0, stream>>>(xb, csr16, offs, deg, (unsigned*)meanb);
  k_fused_mfma<<<782, 512, 0, stream>>>(meanb, xb, bmh, wmh, b_l, b_mlp, out);
}